// Round 6
// baseline (162.357 us; speedup 1.0000x reference)
//
#include <hip/hip_runtime.h>
#include <hip/hip_cooperative_groups.h>
#include <stdint.h>

namespace cg = cooperative_groups;

#define V_N    4096
#define B_N    4
#define C_N    128
#define POOL_N 1024   // V_N / POOLING_RATE
#define K_NBR  4

// ---------------- Threefry-2x32 (20 rounds), exactly as JAX lowers it ----
__host__ __device__ __forceinline__ void tf2x32(uint32_t k0, uint32_t k1,
                                                uint32_t x0, uint32_t x1,
                                                uint32_t& o0, uint32_t& o1) {
  uint32_t ks[3] = {k0, k1, k0 ^ k1 ^ 0x1BD11BDAu};
  const int R[5][4] = {{13,15,26,6},{17,29,16,24},{13,15,26,6},{17,29,16,24},{13,15,26,6}};
  x0 += ks[0]; x1 += ks[1];
#pragma unroll
  for (int g = 0; g < 5; ++g) {
#pragma unroll
    for (int r = 0; r < 4; ++r) {
      x0 += x1;
      const int rot = R[g][r];
      x1 = (x1 << rot) | (x1 >> (32 - rot));
      x1 ^= x0;
    }
    x0 += ks[(g + 1) % 3];
    x1 += ks[(g + 2) % 3] + (uint32_t)(g + 1);
  }
  o0 = x0; o1 = x1;
}

__device__ __forceinline__ bool lexlt(float d1, int i1, float d2, int i2) {
  return d1 < d2 || (d1 == d2 && i1 < i2);
}
__device__ __forceinline__ void ce(float& da, int& ia, float& db, int& ib) {
  if (!lexlt(da, ia, db, ib)) {
    float td = da; da = db; db = td;
    int   ti = ia; ia = ib; ib = ti;
  }
}

// ---------------- Cooperative mega-kernel: keygen | perm | knn | pool -----
__global__ __launch_bounds__(512, 4)
void mega_kernel(uint32_t s10, uint32_t s11, uint32_t s20, uint32_t s21,
                 const float* __restrict__ verts, const float* __restrict__ fm,
                 uint32_t* __restrict__ keys,      // [8192] = b1 | b2
                 int* __restrict__ permg,          // [4096]
                 int* __restrict__ nbr,            // [4*1024*4]
                 float* __restrict__ out) {
  __shared__ union U {
    struct {
      uint32_t b1[V_N];                 // 16 KB (contiguous with b2 for uint4 load)
      uint32_t b2[V_N];                 // 16 KB
      int      partial[64][8];
      int      pbuf[8];
      uint32_t kbuf[8];
    } pm;
    float4 v4[V_N * 3 / 4];             // 48 KB packed xyz / fm slice
  } lds;

  cg::grid_group grid = cg::this_grid();
  const int tid = threadIdx.x;
  const int bid = blockIdx.x;

  // ======== Phase 0: keygen once across the grid ==========================
  {
    const int g = bid * 512 + tid;
    if (g < V_N) {
      uint32_t h, l;
      tf2x32(s10, s11, 0u, (uint32_t)g, h, l);
      keys[g] = h ^ l;
    } else if (g < 2 * V_N) {
      uint32_t h, l;
      tf2x32(s20, s21, 0u, (uint32_t)(g - V_N), h, l);
      keys[g] = h ^ l;
    }
  }
  grid.sync();

  // ======== Phase 1: 2-round permutation via rank counting-sort ===========
  // final[r2(r1(e))] = e; thread block handles 8 elements, 64 segments.
  {
    uint4* kd = (uint4*)lds.pm.b1;                 // b1|b2 contiguous: 2048 uint4
    const uint4* ks4 = (const uint4*)keys;
#pragma unroll
    for (int w = 0; w < 4; ++w) kd[tid + 512 * w] = ks4[tid + 512 * w];
    __syncthreads();

    const int q   = tid & 7;                       // element slot in block
    const int seg = tid >> 3;                      // segment 0..63
    const int e   = bid * 8 + q;                   // element 0..4095
    const uint32_t ke = lds.pm.b1[e];

    int r = 0;
#pragma unroll 8
    for (int i = 0; i < 64; ++i) {
      const int m = seg + 64 * i;
      const uint32_t bm = lds.pm.b1[m];
      r += (bm < ke || (bm == ke && m < e)) ? 1 : 0;
    }
    lds.pm.partial[seg][q] = r;
    __syncthreads();
    if (tid < 8) {
      int p = 0;
#pragma unroll 8
      for (int s = 0; s < 64; ++s) p += lds.pm.partial[s][tid];
      lds.pm.pbuf[tid] = p;
      lds.pm.kbuf[tid] = lds.pm.b2[p];
    }
    __syncthreads();

    const int p = lds.pm.pbuf[q];
    const uint32_t kp = lds.pm.kbuf[q];
    r = 0;
#pragma unroll 8
    for (int i = 0; i < 64; ++i) {
      const int m = seg + 64 * i;
      const uint32_t bm = lds.pm.b2[m];
      r += (bm < kp || (bm == kp && m < p)) ? 1 : 0;
    }
    lds.pm.partial[seg][q] = r;
    __syncthreads();
    if (tid < 8) {
      int r2 = 0;
#pragma unroll 8
      for (int s = 0; s < 64; ++s) r2 += lds.pm.partial[s][tid];
      permg[r2] = bid * 8 + tid;
    }
  }
  grid.sync();

  // ======== Phase 2: kNN, one query per wave + bitonic shuffle merge ======
  // dist replicates reference fp32 rounding exactly (validated absmax=0).
  {
    const int b = bid >> 7;                        // batch 0..3
    const int g = bid & 127;                       // query group
    const float* sv = (const float*)lds.v4;
    const float4* vb4 = (const float4*)(verts + (size_t)b * V_N * 3);
#pragma unroll
    for (int w = 0; w < 6; ++w)
      lds.v4[tid + 512 * w] = vb4[tid + 512 * w];
    __syncthreads();

    const int lane = tid & 63;
    const int wv   = tid >> 6;                     // wave id 0..7 = query slot
    const int qid  = g * 8 + wv;                   // 0..1023 output slot
    const int qv   = permg[qid];                   // sampled vertex index
    const float qx = sv[3 * qv], qy = sv[3 * qv + 1], qz = sv[3 * qv + 2];
    const float qq = __fadd_rn(__fadd_rn(__fmul_rn(qx, qx), __fmul_rn(qy, qy)),
                               __fmul_rn(qz, qz));

    float bd0 = 1e30f, bd1 = 1e30f, bd2 = 1e30f, bd3 = 1e30f;
    int   bi0 = -1, bi1 = -1, bi2 = -1, bi3 = -1;

#define EVAL(X, Y, Z, MC)                                                     \
  do {                                                                        \
    const float x_ = (X), y_ = (Y), z_ = (Z);                                 \
    const int mc_ = (MC);                                                     \
    const float qm_ = __fadd_rn(__fadd_rn(__fmul_rn(x_, x_),                  \
                                          __fmul_rn(y_, y_)),                 \
                                __fmul_rn(z_, z_));                           \
    const float in_ = __fmaf_rn(qz, z_, __fmaf_rn(qy, y_, __fmul_rn(qx, x_)));\
    const float dist = __fadd_rn(__fmaf_rn(-2.0f, in_, qm_), qq);             \
    if (mc_ != qv && dist < bd3) {                                            \
      if (dist < bd2) {                                                       \
        bd3 = bd2; bi3 = bi2;                                                 \
        if (dist < bd1) {                                                     \
          bd2 = bd1; bi2 = bi1;                                               \
          if (dist < bd0) { bd1 = bd0; bi1 = bi0; bd0 = dist; bi0 = mc_; }    \
          else            { bd1 = dist; bi1 = mc_; }                          \
        } else { bd2 = dist; bi2 = mc_; }                                     \
      } else { bd3 = dist; bi3 = mc_; }                                       \
    }                                                                         \
  } while (0)

#pragma unroll 4
    for (int i = 0; i < 16; ++i) {
      const int base = lane + 64 * i;              // 4 candidates per lane-iter
      const float4 c0 = lds.v4[3 * base + 0];
      const float4 c1 = lds.v4[3 * base + 1];
      const float4 c2 = lds.v4[3 * base + 2];
      const int m0 = 4 * base;
      EVAL(c0.x, c0.y, c0.z, m0 + 0);
      EVAL(c0.w, c1.x, c1.y, m0 + 1);
      EVAL(c1.z, c1.w, c2.x, m0 + 2);
      EVAL(c2.y, c2.z, c2.w, m0 + 3);
    }
#undef EVAL

#pragma unroll
    for (int off = 1; off <= 32; off <<= 1) {
      const float e0 = __shfl_xor(bd0, off), e1 = __shfl_xor(bd1, off);
      const float e2 = __shfl_xor(bd2, off), e3 = __shfl_xor(bd3, off);
      const int   f0 = __shfl_xor(bi0, off), f1 = __shfl_xor(bi1, off);
      const int   f2 = __shfl_xor(bi2, off), f3 = __shfl_xor(bi3, off);
      const bool c0 = lexlt(bd0, bi0, e3, f3); bd0 = c0 ? bd0 : e3; bi0 = c0 ? bi0 : f3;
      const bool c1 = lexlt(bd1, bi1, e2, f2); bd1 = c1 ? bd1 : e2; bi1 = c1 ? bi1 : f2;
      const bool c2 = lexlt(bd2, bi2, e1, f1); bd2 = c2 ? bd2 : e1; bi2 = c2 ? bi2 : f1;
      const bool c3 = lexlt(bd3, bi3, e0, f0); bd3 = c3 ? bd3 : e0; bi3 = c3 ? bi3 : f0;
      ce(bd0, bi0, bd2, bi2); ce(bd1, bi1, bd3, bi3);
      ce(bd0, bi0, bd1, bi1); ce(bd2, bi2, bd3, bi3);
    }

    if (lane == 0) {
      ((int4*)nbr)[b * POOL_N + qid] = make_int4(bi0, bi1, bi2, bi3);
      float* ov = out + ((size_t)b * POOL_N + qid) * 3;   // fused vertices_pool
      ov[0] = qx; ov[1] = qy; ov[2] = qz;
    }
  }
  grid.sync();

  // ======== Phase 3: feature max-pool, LDS-staged (b,c) slice =============
  {
    const int bc = bid;                            // b*128 + c
    const int b  = bc >> 7;
    const float* sf = (const float*)lds.v4;
    const float4* src = (const float4*)(fm + (size_t)bc * V_N * 3);
#pragma unroll
    for (int w = 0; w < 6; ++w)
      lds.v4[tid + 512 * w] = src[tid + 512 * w];
    __syncthreads();

    const int j0 = tid * 2;                        // 2 outputs per thread
    const int4* nb4 = (const int4*)(nbr) + b * POOL_N + j0;

    const int4 n0 = nb4[0];
    const float* a0 = sf + n0.x * 3; const float* a1 = sf + n0.y * 3;
    const float* a2 = sf + n0.z * 3; const float* a3 = sf + n0.w * 3;
    const float r00 = fmaxf(fmaxf(a0[0], a1[0]), fmaxf(a2[0], a3[0]));
    const float r01 = fmaxf(fmaxf(a0[1], a1[1]), fmaxf(a2[1], a3[1]));
    const float r02 = fmaxf(fmaxf(a0[2], a1[2]), fmaxf(a2[2], a3[2]));

    const int4 n1 = nb4[1];
    const float* b0 = sf + n1.x * 3; const float* b1 = sf + n1.y * 3;
    const float* b2 = sf + n1.z * 3; const float* b3 = sf + n1.w * 3;
    const float r10 = fmaxf(fmaxf(b0[0], b1[0]), fmaxf(b2[0], b3[0]));
    const float r11 = fmaxf(fmaxf(b0[1], b1[1]), fmaxf(b2[1], b3[1]));
    const float r12 = fmaxf(fmaxf(b0[2], b1[2]), fmaxf(b2[2], b3[2]));

    float2* dst = (float2*)(out + (size_t)B_N * POOL_N * 3 +
                            (size_t)bc * POOL_N * 3 + (size_t)j0 * 3);
    dst[0] = make_float2(r00, r01);
    dst[1] = make_float2(r02, r10);
    dst[2] = make_float2(r11, r12);
  }
}

extern "C" void kernel_launch(void* const* d_in, const int* in_sizes, int n_in,
                              void* d_out, int out_size, void* d_ws, size_t ws_size,
                              hipStream_t stream) {
  const float* verts = (const float*)d_in[0];   // (4, 4096, 3) f32
  const float* fm    = (const float*)d_in[1];   // (4, 128, 4096, 3) f32
  float* out = (float*)d_out;                   // 12288 + 1572864 f32
  uint32_t* keys = (uint32_t*)d_ws;             // [8192] b1|b2
  int* permg = (int*)(keys + 2 * V_N);          // [4096]
  int* nbr   = permg + V_N;                     // [4*1024*4], 16-B aligned

  // Derive both rounds' subkeys on host (deterministic, baked as kernel args).
  // key(42) = (0, 42); foldlike split: next = TF(key,(0,0)), sub = TF(key,(0,1)).
  uint32_t k0 = 0u, k1 = 42u, sub0[2], sub1[2];
  for (int r = 0; r < 2; ++r) {
    uint32_t n0, n1, s0, s1;
    tf2x32(k0, k1, 0u, 0u, n0, n1);
    tf2x32(k0, k1, 0u, 1u, s0, s1);
    sub0[r] = s0; sub1[r] = s1; k0 = n0; k1 = n1;
  }

  uint32_t a0 = sub0[0], a1 = sub1[0], b0 = sub0[1], b1 = sub1[1];
  void* args[] = {&a0, &a1, &b0, &b1, &verts, &fm, &keys, &permg, &nbr, &out};
  hipLaunchCooperativeKernel((const void*)mega_kernel, dim3(512), dim3(512),
                             args, 0, stream);
}

// Round 7
// 27.862 us; speedup vs baseline: 5.8272x; 5.8272x over previous
//
#include <hip/hip_runtime.h>
#include <stdint.h>
#include <algorithm>
#include <numeric>

#define V_N    4096
#define B_N    4
#define C_N    128
#define POOL_N 1024   // V_N / POOLING_RATE
#define K_NBR  4

// ---------------- Threefry-2x32 (20 rounds), exactly as JAX lowers it ----
// Host-only now: the permutation is input-independent, computed on CPU each
// call (deterministic), and shipped as a 2 KB kernarg struct.
static inline void tf2x32(uint32_t k0, uint32_t k1, uint32_t x0, uint32_t x1,
                          uint32_t& o0, uint32_t& o1) {
  uint32_t ks[3] = {k0, k1, k0 ^ k1 ^ 0x1BD11BDAu};
  const int R[5][4] = {{13,15,26,6},{17,29,16,24},{13,15,26,6},{17,29,16,24},{13,15,26,6}};
  x0 += ks[0]; x1 += ks[1];
  for (int g = 0; g < 5; ++g) {
    for (int r = 0; r < 4; ++r) {
      x0 += x1;
      const int rot = R[g][r];
      x1 = (x1 << rot) | (x1 >> (32 - rot));
      x1 ^= x0;
    }
    x0 += ks[(g + 1) % 3];
    x1 += ks[(g + 2) % 3] + (uint32_t)(g + 1);
  }
  o0 = x0; o1 = x1;
}

struct SampleIdx { unsigned short v[POOL_N]; };   // 2048 B kernarg payload

__device__ __forceinline__ bool lexlt(float d1, int i1, float d2, int i2) {
  return d1 < d2 || (d1 == d2 && i1 < i2);
}
__device__ __forceinline__ void ce(float& da, int& ia, float& db, int& ib) {
  if (!lexlt(da, ia, db, ib)) {
    float td = da; da = db; db = td;
    int   ti = ia; ia = ib; ib = ti;
  }
}

// ---------------- Kernel 1: kNN, one query per WAVE + shuffle merge -------
// dist replicates reference fp32 rounding exactly (validated absmax=0):
//   quad  = (x*x + y*y) + z*z ; inner = fmaf(z,z',fmaf(y,y',x*x'))
//   dist  = ((-2*inner) + quad_m) + quad_n
// Selection: lexicographic (dist, idx) top-4 excluding self == top_k[1:].
__global__ __launch_bounds__(512) void knn_kernel(const float* __restrict__ verts,
                                                  const SampleIdx si,
                                                  int* __restrict__ nbr,
                                                  float* __restrict__ outV) {
  __shared__ float4 sv4[V_N * 3 / 4];           // 48 KB packed xyz
  const float* sv = (const float*)sv4;
  const int tid = threadIdx.x;
  const int b = blockIdx.y;
  const float4* vb4 = (const float4*)(verts + (size_t)b * V_N * 3);
#pragma unroll
  for (int w = 0; w < 6; ++w)
    sv4[tid + 512 * w] = vb4[tid + 512 * w];
  __syncthreads();

  const int lane = tid & 63;
  const int wv   = tid >> 6;                    // wave id 0..7 = query slot
  const int qid  = blockIdx.x * 8 + wv;         // 0..1023 output slot
  const int qv   = si.v[qid];                   // sampled vertex (kernarg)
  const float qx = sv[3 * qv], qy = sv[3 * qv + 1], qz = sv[3 * qv + 2];
  const float qq = __fadd_rn(__fadd_rn(__fmul_rn(qx, qx), __fmul_rn(qy, qy)),
                             __fmul_rn(qz, qz));

  float bd0 = 1e30f, bd1 = 1e30f, bd2 = 1e30f, bd3 = 1e30f;
  int   bi0 = -1, bi1 = -1, bi2 = -1, bi3 = -1;

#define EVAL(X, Y, Z, MC)                                                     \
  do {                                                                        \
    const float x_ = (X), y_ = (Y), z_ = (Z);                                 \
    const int mc_ = (MC);                                                     \
    const float qm_ = __fadd_rn(__fadd_rn(__fmul_rn(x_, x_),                  \
                                          __fmul_rn(y_, y_)),                 \
                                __fmul_rn(z_, z_));                           \
    const float in_ = __fmaf_rn(qz, z_, __fmaf_rn(qy, y_, __fmul_rn(qx, x_)));\
    const float dist = __fadd_rn(__fmaf_rn(-2.0f, in_, qm_), qq);             \
    if (mc_ != qv && dist < bd3) {                                            \
      if (dist < bd2) {                                                       \
        bd3 = bd2; bi3 = bi2;                                                 \
        if (dist < bd1) {                                                     \
          bd2 = bd1; bi2 = bi1;                                               \
          if (dist < bd0) { bd1 = bd0; bi1 = bi0; bd0 = dist; bi0 = mc_; }    \
          else            { bd1 = dist; bi1 = mc_; }                          \
        } else { bd2 = dist; bi2 = mc_; }                                     \
      } else { bd3 = dist; bi3 = mc_; }                                       \
    }                                                                         \
  } while (0)

#pragma unroll 4
  for (int i = 0; i < 16; ++i) {
    const int base = lane + 64 * i;             // 4 candidates per lane-iter
    const float4 c0 = sv4[3 * base + 0];
    const float4 c1 = sv4[3 * base + 1];
    const float4 c2 = sv4[3 * base + 2];
    const int m0 = 4 * base;
    EVAL(c0.x, c0.y, c0.z, m0 + 0);
    EVAL(c0.w, c1.x, c1.y, m0 + 1);
    EVAL(c1.z, c1.w, c2.x, m0 + 2);
    EVAL(c2.y, c2.z, c2.w, m0 + 3);
  }
#undef EVAL

  // 6-stage butterfly: merge two sorted 4-lists -> sorted top-4 (bitonic).
#pragma unroll
  for (int off = 1; off <= 32; off <<= 1) {
    const float e0 = __shfl_xor(bd0, off), e1 = __shfl_xor(bd1, off);
    const float e2 = __shfl_xor(bd2, off), e3 = __shfl_xor(bd3, off);
    const int   f0 = __shfl_xor(bi0, off), f1 = __shfl_xor(bi1, off);
    const int   f2 = __shfl_xor(bi2, off), f3 = __shfl_xor(bi3, off);
    const bool c0 = lexlt(bd0, bi0, e3, f3); bd0 = c0 ? bd0 : e3; bi0 = c0 ? bi0 : f3;
    const bool c1 = lexlt(bd1, bi1, e2, f2); bd1 = c1 ? bd1 : e2; bi1 = c1 ? bi1 : f2;
    const bool c2 = lexlt(bd2, bi2, e1, f1); bd2 = c2 ? bd2 : e1; bi2 = c2 ? bi2 : f1;
    const bool c3 = lexlt(bd3, bi3, e0, f0); bd3 = c3 ? bd3 : e0; bi3 = c3 ? bi3 : f0;
    ce(bd0, bi0, bd2, bi2); ce(bd1, bi1, bd3, bi3);
    ce(bd0, bi0, bd1, bi1); ce(bd2, bi2, bd3, bi3);
  }

  if (lane == 0) {
    ((int4*)nbr)[b * POOL_N + qid] = make_int4(bi0, bi1, bi2, bi3);
    float* ov = outV + ((size_t)b * POOL_N + qid) * 3;   // fused vertices_pool
    ov[0] = qx; ov[1] = qy; ov[2] = qz;
  }
}

// ---------------- Kernel 2: feature max-pool, LDS-staged (b,c) slice ------
// One block per (b,c): coalesced float4 read of the 48 KB slice into LDS,
// gather+max from LDS, contiguous float4 stores. Exact max of 4 floats.
__global__ __launch_bounds__(256) void pool_kernel(const float* __restrict__ fm,
                                                   const int* __restrict__ nbr,
                                                   float* __restrict__ outF) {
  __shared__ float4 sf4[V_N * 3 / 4];           // 48 KB
  const float* sf = (const float*)sf4;
  const int tid = threadIdx.x;
  const int bc = blockIdx.x;                    // 0..511 = b*128 + c
  const int b  = bc >> 7;
  const float4* src = (const float4*)(fm + (size_t)bc * V_N * 3);
#pragma unroll
  for (int w = 0; w < 12; ++w)
    sf4[tid + 256 * w] = src[tid + 256 * w];
  __syncthreads();

  const int j0 = tid * 4;                       // 4 outputs per thread
  const int4* nb4 = (const int4*)(nbr) + b * POOL_N + j0;

  const int4 n0 = nb4[0];
  const float* a0 = sf + n0.x * 3; const float* a1 = sf + n0.y * 3;
  const float* a2 = sf + n0.z * 3; const float* a3 = sf + n0.w * 3;
  const float r00 = fmaxf(fmaxf(a0[0], a1[0]), fmaxf(a2[0], a3[0]));
  const float r01 = fmaxf(fmaxf(a0[1], a1[1]), fmaxf(a2[1], a3[1]));
  const float r02 = fmaxf(fmaxf(a0[2], a1[2]), fmaxf(a2[2], a3[2]));

  const int4 n1 = nb4[1];
  const float* b0 = sf + n1.x * 3; const float* b1 = sf + n1.y * 3;
  const float* b2 = sf + n1.z * 3; const float* b3 = sf + n1.w * 3;
  const float r10 = fmaxf(fmaxf(b0[0], b1[0]), fmaxf(b2[0], b3[0]));
  const float r11 = fmaxf(fmaxf(b0[1], b1[1]), fmaxf(b2[1], b3[1]));
  const float r12 = fmaxf(fmaxf(b0[2], b1[2]), fmaxf(b2[2], b3[2]));

  const int4 n2 = nb4[2];
  const float* c0 = sf + n2.x * 3; const float* c1 = sf + n2.y * 3;
  const float* c2 = sf + n2.z * 3; const float* c3 = sf + n2.w * 3;
  const float r20 = fmaxf(fmaxf(c0[0], c1[0]), fmaxf(c2[0], c3[0]));
  const float r21 = fmaxf(fmaxf(c0[1], c1[1]), fmaxf(c2[1], c3[1]));
  const float r22 = fmaxf(fmaxf(c0[2], c1[2]), fmaxf(c2[2], c3[2]));

  const int4 n3 = nb4[3];
  const float* d0 = sf + n3.x * 3; const float* d1 = sf + n3.y * 3;
  const float* d2 = sf + n3.z * 3; const float* d3 = sf + n3.w * 3;
  const float r30 = fmaxf(fmaxf(d0[0], d1[0]), fmaxf(d2[0], d3[0]));
  const float r31 = fmaxf(fmaxf(d0[1], d1[1]), fmaxf(d2[1], d3[1]));
  const float r32 = fmaxf(fmaxf(d0[2], d1[2]), fmaxf(d2[2], d3[2]));

  float4* dst = (float4*)(outF + (size_t)bc * POOL_N * 3 + (size_t)j0 * 3);
  dst[0] = make_float4(r00, r01, r02, r10);
  dst[1] = make_float4(r11, r12, r20, r21);
  dst[2] = make_float4(r22, r30, r31, r32);
}

extern "C" void kernel_launch(void* const* d_in, const int* in_sizes, int n_in,
                              void* d_out, int out_size, void* d_ws, size_t ws_size,
                              hipStream_t stream) {
  const float* verts = (const float*)d_in[0];   // (4, 4096, 3) f32
  const float* fm    = (const float*)d_in[1];   // (4, 128, 4096, 3) f32
  float* out = (float*)d_out;                   // 12288 + 1572864 f32
  int* nbr  = (int*)d_ws;                       // [4*1024*4], 16-B aligned

  // ---- Host-side permutation (input-independent, recomputed every call) ---
  // key(42) = (0, 42); 2 rounds of foldlike split -> random_bits -> stable
  // sort; identical rank semantics to the device version validated absmax=0.
  uint32_t k0 = 0u, k1 = 42u, sub0[2], sub1[2];
  for (int r = 0; r < 2; ++r) {
    uint32_t n0, n1, s0, s1;
    tf2x32(k0, k1, 0u, 0u, n0, n1);
    tf2x32(k0, k1, 0u, 1u, s0, s1);
    sub0[r] = s0; sub1[r] = s1; k0 = n0; k1 = n1;
  }
  static thread_local uint32_t b1[V_N], b2[V_N];
  static thread_local int ord1[V_N], ord2[V_N];
  for (int i = 0; i < V_N; ++i) {
    uint32_t h, l;
    tf2x32(sub0[0], sub1[0], 0u, (uint32_t)i, h, l); b1[i] = h ^ l;
    tf2x32(sub0[1], sub1[1], 0u, (uint32_t)i, h, l); b2[i] = h ^ l;
  }
  std::iota(ord1, ord1 + V_N, 0);
  std::stable_sort(ord1, ord1 + V_N, [](int a, int b_) { return b1[a] < b1[b_]; });
  std::iota(ord2, ord2 + V_N, 0);
  std::stable_sort(ord2, ord2 + V_N, [](int a, int b_) { return b2[a] < b2[b_]; });
  SampleIdx si;
  for (int j = 0; j < POOL_N; ++j)
    si.v[j] = (unsigned short)ord1[ord2[j]];    // perm[j] = v1[ord2[j]]

  knn_kernel<<<dim3(POOL_N / 8, B_N), 512, 0, stream>>>(verts, si, nbr, out);
  pool_kernel<<<B_N * C_N, 256, 0, stream>>>(fm, nbr, out + B_N * POOL_N * 3);
}